// Round 7
// baseline (234.346 us; speedup 1.0000x reference)
//
#include <hip/hip_runtime.h>
#include <hip/hip_bf16.h>
#include <stdint.h>

#define BB   8
#define LL   1024
#define LOO  1024
#define HH   768
#define VV   4096
#define OUTW 5120   // VV + LL
#define EMAX 256    // tags sorted from [0,256) => emitted <= 255

typedef unsigned short ushort_t;
typedef __attribute__((ext_vector_type(4))) float   f32x4;
typedef __attribute__((ext_vector_type(8))) __bf16  bf16x8;
typedef __attribute__((ext_vector_type(4))) float   float4v;
typedef __attribute__((ext_vector_type(4))) int     int4v;

static __device__ __forceinline__ ushort_t f2bf(float f) {
    union { float f; uint32_t u; } v; v.f = f;
    uint32_t u = v.u;
    uint32_t r = (u + 0x7fffu + ((u >> 16) & 1u)) >> 16;
    return (ushort_t)r;
}

// One kernel, 512 blocks x 256 threads. Block bid: batch b = bid>>6, rg = bid&63.
//   Owns out rows [rg*16, rg*16+16) of batch b, and produces attn rows
//   [rg*4, rg*4+4).
// Waves 2,3: copy lm rows 0..11 + fill (start immediately, depend on nothing).
// Waves 0,1: wave-local tag scan -> 2 attn rows each -> publish done[b] ->
//   spin for done[b]==128 -> barrier-free per-wave GEMM half (16x128) ->
//   copy rows 12..15.
__global__ __launch_bounds__(256) void fused_all_kernel(
        const float* __restrict__ h1,      // [BB][LL][HH]
        const float* __restrict__ h2,      // [BB][LOO][HH]
        const float* __restrict__ lm,      // [BB][LOO][VV]
        const int*   __restrict__ tags,    // [BB][LL]
        ushort_t*    __restrict__ attn,    // ws bf16 [BB][EMAX][HH]
        int*         __restrict__ done,    // ws [BB], zeroed via memsetAsync
        float*       __restrict__ out) {   // [BB][LOO][OUTW]
    // per-wave (w=0,1) 18KB region: A tile 2KB (also runpos scratch), B 16KB
    __shared__ char smem[36864];

    const int bid  = blockIdx.x;
    const int b    = bid >> 6;
    const int rg   = bid & 63;
    const int r0   = rg << 4;            // first of 16 out rows
    const int tid  = threadIdx.x;
    const int lane = tid & 63;
    const int w    = tid >> 6;

    const float4v* lm4 = (const float4v*)lm + ((size_t)b * LOO + r0) * (VV / 4);
    float4v*       o4  = (float4v*)out + ((size_t)b * LOO + r0) * (OUTW / 4);
    const float4v  fv  = {-100.f, -100.f, -100.f, -100.f};

    if (w >= 2) {
        // ---------------- pure copy waves: rows [ (w-2)*6, +6 ) ----------------
        for (int r = (w - 2) * 6; r < (w - 2) * 6 + 6; ++r) {
#pragma unroll
            for (int it = 0; it < 16; it += 4) {
                float4v v0 = __builtin_nontemporal_load(&lm4[r * 1024 + (it + 0) * 64 + lane]);
                float4v v1 = __builtin_nontemporal_load(&lm4[r * 1024 + (it + 1) * 64 + lane]);
                float4v v2 = __builtin_nontemporal_load(&lm4[r * 1024 + (it + 2) * 64 + lane]);
                float4v v3 = __builtin_nontemporal_load(&lm4[r * 1024 + (it + 3) * 64 + lane]);
                __builtin_nontemporal_store(v0, &o4[r * 1280 + (it + 0) * 64 + lane]);
                __builtin_nontemporal_store(v1, &o4[r * 1280 + (it + 1) * 64 + lane]);
                __builtin_nontemporal_store(v2, &o4[r * 1280 + (it + 2) * 64 + lane]);
                __builtin_nontemporal_store(v3, &o4[r * 1280 + (it + 3) * 64 + lane]);
            }
#pragma unroll
            for (int it = 0; it < 3; ++it)
                __builtin_nontemporal_store(fv, &o4[r * 1280 + 1088 + it * 64 + lane]);
        }
        return;
    }

    // ================= waves 0,1 =================
    char* Aw = smem + w * 18432;          // 2KB A tile / runpos scratch
    char* Bw = smem + w * 18432 + 2048;   // 16KB B half-tile

    // ---- wave-local tag scan (no cross-wave sync) ----
    const int* tg = tags + b * LL;
    int p0 = lane * 16;
    int tvv[17];
    tvv[0] = (lane == 0) ? -2 : tg[p0 - 1];
#pragma unroll
    for (int q = 0; q < 4; ++q) {
        int4v t4 = ((const int4v*)(tg + p0))[q];
        tvv[1 + 4 * q] = t4[0]; tvv[2 + 4 * q] = t4[1];
        tvv[3 + 4 * q] = t4[2]; tvv[4 + 4 * q] = t4[3];
    }
    int st_[16], c = 0;
#pragma unroll
    for (int i = 0; i < 16; ++i) { st_[i] = (tvv[i + 1] != tvv[i]); c += st_[i]; }
    int incl = c;
#pragma unroll
    for (int off = 1; off < 64; off <<= 1) {
        int n = __shfl_up(incl, off, 64);
        if (lane >= off) incl += n;
    }
    int total = __shfl(incl, 63, 64);     // total runs (<=256)
    int em    = total - 1;                // trailing open run dropped
    int* runpos = (int*)Aw;               // 257 ints, scratch in A region
    int base = incl - c;
#pragma unroll
    for (int i = 0; i < 16; ++i)
        if (st_[i]) runpos[base++] = p0 + i;
    if (lane == 63) runpos[total] = LL;
    asm volatile("s_waitcnt lgkmcnt(0)" ::: "memory");

    // ---- produce 2 attn rows: r = rg*4 + w*2 + rr ----
#pragma unroll
    for (int rr = 0; rr < 2; ++rr) {
        int r = (rg << 2) + (w << 1) + rr;
        ushort_t* arow = attn + ((size_t)b * EMAX + r) * HH;
        if (r >= em) {
#pragma unroll
            for (int j = 0; j < 12; ++j) arow[lane + 64 * j] = 0;
        } else {
            int s = runpos[r], e = runpos[r + 1];
            float inv = 1.0f / (float)(e - s);
            float a[12];
#pragma unroll
            for (int j = 0; j < 12; ++j) a[j] = 0.f;
            for (int p = s; p < e; ++p) {
                const float* row = h1 + ((size_t)b * LL + p) * HH;
#pragma unroll
                for (int j = 0; j < 12; ++j) a[j] += row[lane + 64 * j];
            }
#pragma unroll
            for (int j = 0; j < 12; ++j) arow[lane + 64 * j] = f2bf(a[j] * inv);
        }
    }

    // ---- publish (release) then wait for the batch's 128 producer waves ----
    if (lane == 0)
        __hip_atomic_fetch_add(&done[b], 1, __ATOMIC_RELEASE, __HIP_MEMORY_SCOPE_AGENT);
    while (__hip_atomic_load(&done[b], __ATOMIC_ACQUIRE, __HIP_MEMORY_SCOPE_AGENT) < 128)
        __builtin_amdgcn_s_sleep(2);

    // ---- barrier-free GEMM: this wave's 16x128 half (cols w*128..w*128+128) ----
    const float*    Ab = h2 + ((size_t)b * LOO + r0) * HH;
    const ushort_t* Bb = attn + (size_t)b * EMAX * HH;

    f32x4 acc[8];
#pragma unroll
    for (int i = 0; i < 8; ++i) acc[i] = (f32x4){0.f, 0.f, 0.f, 0.f};

    for (int k0 = 0; k0 < HH; k0 += 64) {
        // B half: 128 rows x 64 bf16, linear LDS dest + pre-swizzled source
#pragma unroll
        for (int i = 0; i < 16; ++i) {
            int off = i * 1024 + lane * 16;
            int row = off >> 7;
            int cb  = off & 127;
            int scb = cb ^ ((row & 7) << 4);
            const ushort_t* gb = Bb + (size_t)((w << 7) + row) * HH + k0 + (scb >> 1);
            __builtin_amdgcn_global_load_lds(
                (const __attribute__((address_space(1))) void*)gb,
                (__attribute__((address_space(3))) void*)(Bw + off), 16, 0, 0);
        }
        // A tile: 16x64 f32 -> bf16, reg-staged, swizzled ds_write
        {
            const float* pa = Ab + (size_t)(lane & 15) * HH + k0 + ((lane >> 4) << 4);
            f32x4 v0 = ((const f32x4*)pa)[0];
            f32x4 v1 = ((const f32x4*)pa)[1];
            f32x4 v2 = ((const f32x4*)pa)[2];
            f32x4 v3 = ((const f32x4*)pa)[3];
            bf16x8 t0, t1;
            t0[0] = (__bf16)v0[0]; t0[1] = (__bf16)v0[1]; t0[2] = (__bf16)v0[2]; t0[3] = (__bf16)v0[3];
            t0[4] = (__bf16)v1[0]; t0[5] = (__bf16)v1[1]; t0[6] = (__bf16)v1[2]; t0[7] = (__bf16)v1[3];
            t1[0] = (__bf16)v2[0]; t1[1] = (__bf16)v2[1]; t1[2] = (__bf16)v2[2]; t1[3] = (__bf16)v2[3];
            t1[4] = (__bf16)v3[0]; t1[5] = (__bf16)v3[1]; t1[6] = (__bf16)v3[2]; t1[7] = (__bf16)v3[3];
            int ar = lane & 15;
            int bo = (lane >> 4) << 5;
            int sw = (ar & 7) << 4;
            *(bf16x8*)(Aw + ar * 128 + (bo ^ sw))        = t0;
            *(bf16x8*)(Aw + ar * 128 + ((bo + 16) ^ sw)) = t1;
        }
        asm volatile("s_waitcnt vmcnt(0)" ::: "memory");
        __builtin_amdgcn_sched_barrier(0);

#pragma unroll
        for (int ks = 0; ks < 2; ++ks) {
            int kb = (ks << 6) + ((lane >> 4) << 4);
            int ar = lane & 15;
            bf16x8 af = *(const bf16x8*)(Aw + ar * 128 + (kb ^ ((ar & 7) << 4)));
#pragma unroll
            for (int ni = 0; ni < 8; ++ni) {
                int br = (ni << 4) + (lane & 15);
                bf16x8 bf = *(const bf16x8*)(Bw + br * 128 + (kb ^ ((br & 7) << 4)));
                acc[ni] = __builtin_amdgcn_mfma_f32_16x16x32_bf16(af, bf, acc[ni], 0, 0, 0);
            }
        }
    }

    // epilogue: C/D layout col=lane&15, row=(lane>>4)*4+reg
    {
        float* outb = out + ((size_t)b * LOO + r0) * OUTW + VV;
#pragma unroll
        for (int ni = 0; ni < 8; ++ni) {
            int col = (w << 7) + (ni << 4) + (lane & 15);
            float badd = (col < em) ? 0.0f : -100.0f;
            int rbase = (lane >> 4) << 2;
#pragma unroll
            for (int rrr = 0; rrr < 4; ++rrr)
                outb[(size_t)(rbase + rrr) * OUTW + col] = acc[ni][rrr] + badd;
        }
    }

    // ---- tail copy: rows 12..15 (2 per wave) ----
    for (int r = 12 + w * 2; r < 14 + w * 2; ++r) {
#pragma unroll
        for (int it = 0; it < 16; it += 4) {
            float4v v0 = __builtin_nontemporal_load(&lm4[r * 1024 + (it + 0) * 64 + lane]);
            float4v v1 = __builtin_nontemporal_load(&lm4[r * 1024 + (it + 1) * 64 + lane]);
            float4v v2 = __builtin_nontemporal_load(&lm4[r * 1024 + (it + 2) * 64 + lane]);
            float4v v3 = __builtin_nontemporal_load(&lm4[r * 1024 + (it + 3) * 64 + lane]);
            __builtin_nontemporal_store(v0, &o4[r * 1280 + (it + 0) * 64 + lane]);
            __builtin_nontemporal_store(v1, &o4[r * 1280 + (it + 1) * 64 + lane]);
            __builtin_nontemporal_store(v2, &o4[r * 1280 + (it + 2) * 64 + lane]);
            __builtin_nontemporal_store(v3, &o4[r * 1280 + (it + 3) * 64 + lane]);
        }
#pragma unroll
        for (int it = 0; it < 3; ++it)
            __builtin_nontemporal_store(fv, &o4[r * 1280 + 1088 + it * 64 + lane]);
    }
}

extern "C" void kernel_launch(void* const* d_in, const int* in_sizes, int n_in,
                              void* d_out, int out_size, void* d_ws, size_t ws_size,
                              hipStream_t stream) {
    const float* h1   = (const float*)d_in[0];   // [8,1024,768]
    const float* h2   = (const float*)d_in[1];   // [8,1024,768]
    const float* lm   = (const float*)d_in[2];   // [8,1024,4096]
    const int*   tags = (const int*)d_in[3];     // [8,1024]
    float* out = (float*)d_out;                  // [8,1024,5120]

    char* ws = (char*)d_ws;
    ushort_t* attn = (ushort_t*)ws;              // 3,145,728 B
    int*      done = (int*)(ws + 3145728);       // 32 B, must be 0 each call

    hipMemsetAsync(done, 0, BB * sizeof(int), stream);
    fused_all_kernel<<<512, 256, 0, stream>>>(h1, h2, lm, tags, attn, done, out);
}

// Round 8
// 89.041 us; speedup vs baseline: 2.6319x; 2.6319x over previous
//
#include <hip/hip_runtime.h>
#include <hip/hip_bf16.h>
#include <stdint.h>

#define BB   8
#define LL   1024
#define LOO  1024
#define HH   768
#define VV   4096
#define OUTW 5120   // VV + LL
#define EMAX 256    // tags sorted from [0,256) => emitted <= 255

typedef unsigned short ushort_t;
typedef __attribute__((ext_vector_type(4))) float   f32x4;
typedef __attribute__((ext_vector_type(8))) __bf16  bf16x8;
typedef __attribute__((ext_vector_type(4))) __bf16  bf16x4;
typedef __attribute__((ext_vector_type(4))) float   float4v;
typedef __attribute__((ext_vector_type(4))) int     int4v;

static __device__ __forceinline__ ushort_t f2bf(float f) {
    union { float f; uint32_t u; } v; v.f = f;
    uint32_t u = v.u;
    uint32_t r = (u + 0x7fffu + ((u >> 16) & 1u)) >> 16;
    return (ushort_t)r;
}

// ---- K1: streaming segment means -> bf16 attn [BB][EMAX][HH] ----
// grid (16,3,8): 16 row-chunks of 64, 3 col-chunks of 256, 8 batches.
// Each block: in-block tag scan (cheap, redundant), owns segments whose
// START is in its 64-row window, streams h1 coalescedly (no scatter kernel).
__global__ __launch_bounds__(256) void attn_stream_kernel(
        const float* __restrict__ h1,
        const int* __restrict__ tags,
        ushort_t* __restrict__ attn,
        int* __restrict__ emitted_out) {
    const int rc  = blockIdx.x;          // 0..15
    const int cc  = blockIdx.y;          // 0..2
    const int b   = blockIdx.z;
    const int tid = threadIdx.x;

    __shared__ int stags[LL];            // 4 KB
    __shared__ int cnt[256];
    __shared__ int runpos[EMAX + 1];

    ((int4v*)stags)[tid] = ((const int4v*)(tags + b * LL))[tid];
    __syncthreads();

    int p0 = tid * 4;
    int st[4];
    int prevm1 = (p0 == 0) ? -2 : stags[p0 - 1];
    st[0] = (p0 == 0) || (stags[p0] != prevm1);
    st[1] = (stags[p0 + 1] != stags[p0]);
    st[2] = (stags[p0 + 2] != stags[p0 + 1]);
    st[3] = (stags[p0 + 3] != stags[p0 + 2]);
    int c4 = st[0] + st[1] + st[2] + st[3];
    cnt[tid] = c4;
    __syncthreads();
    for (int off = 1; off < 256; off <<= 1) {
        int v = cnt[tid];
        int a = (tid >= off) ? cnt[tid - off] : 0;
        __syncthreads();
        cnt[tid] = v + a;
        __syncthreads();
    }
    int total = cnt[255];                // total runs (<= 256, tags sorted)
    int base = cnt[tid] - c4;            // exclusive prefix
#pragma unroll
    for (int j = 0; j < 4; ++j)
        if (st[j]) runpos[base++] = p0 + j;
    if (tid == 0) runpos[total] = LL;
    __syncthreads();

    int em = total - 1;                  // trailing open run dropped
    if (rc == 0 && cc == 0 && tid == 0) emitted_out[b] = em;

    // segments with start in [rc*64, rc*64+64): binary search (uniform)
    const int rlo = rc << 6, rhi = rlo + 64;
    int lo;
    { int a = 0, z = total;
      while (a < z) { int m = (a + z) >> 1; if (runpos[m] < rlo) a = m + 1; else z = m; }
      lo = a; }
    int hi;
    { int a = lo, z = total;
      while (a < z) { int m = (a + z) >> 1; if (runpos[m] < rhi) a = m + 1; else z = m; }
      hi = a; }
    int send = hi < em ? hi : em;

    const int c = (cc << 8) + tid;       // this thread's column
    const float* hb = h1 + (size_t)b * LL * HH + c;
    for (int s = lo; s < send; ++s) {
        int ps = runpos[s], pe = runpos[s + 1];
        float acc = 0.f;
        for (int p = ps; p < pe; ++p) acc += hb[(size_t)p * HH];
        attn[((size_t)b * EMAX + s) * HH + c] = f2bf(acc / (float)(pe - ps));
    }
    // zero rows em..255 (block rc==15 owns this for its col chunk)
    if (rc == 15) {
        for (int r = em; r < EMAX; ++r)
            attn[((size_t)b * EMAX + r) * HH + c] = 0;
    }
}

// ---- K2 mega v3: 64 GEMM blocks + 1024 copy blocks, 512 threads each ----
// GEMM: tile 128x256 (full col range), BK=32, LDS 30KB (80B-padded rows,
//   both operands reg-staged -> pad legal, ~2-way read conflicts = free).
// Copy: 8 rows/block: lm -> out[:, 0:VV] (nt), fill cols [VV+256,VV+LL) -100.
#define NGEMM 64
__global__ __launch_bounds__(512, 4) void mega2_kernel(
        const float* __restrict__ h2,      // f32 [BB][LOO][HH]
        const ushort_t* __restrict__ Bm,   // attn bf16 [BB][EMAX][HH]
        const int* __restrict__ emitted,
        const float* __restrict__ lm,
        float* __restrict__ out) {
    __shared__ char smem[30720];   // A [128][80B] @0 (10240), B [256][80B] @10240

    const int bid = blockIdx.x;
    const int tid = threadIdx.x;

    if (bid >= NGEMM) {
        // ---------------- copy + fill path ----------------
        int cid = bid - NGEMM;             // 0..1023, 8 out-rows each
        const float4v* lm4 = (const float4v*)lm + (size_t)cid * 8 * 1024;
        float4v* o4 = (float4v*)out + (size_t)cid * 8 * 1280;
        const float4v fv = {-100.f, -100.f, -100.f, -100.f};
#pragma unroll
        for (int r = 0; r < 8; r += 2) {
            float4v v0 = __builtin_nontemporal_load(&lm4[(size_t)(r    ) * 1024 + tid]);
            float4v v1 = __builtin_nontemporal_load(&lm4[(size_t)(r    ) * 1024 + tid + 512]);
            float4v v2 = __builtin_nontemporal_load(&lm4[(size_t)(r + 1) * 1024 + tid]);
            float4v v3 = __builtin_nontemporal_load(&lm4[(size_t)(r + 1) * 1024 + tid + 512]);
            __builtin_nontemporal_store(v0, &o4[(size_t)(r    ) * 1280 + tid]);
            __builtin_nontemporal_store(v1, &o4[(size_t)(r    ) * 1280 + tid + 512]);
            __builtin_nontemporal_store(v2, &o4[(size_t)(r + 1) * 1280 + tid]);
            __builtin_nontemporal_store(v3, &o4[(size_t)(r + 1) * 1280 + tid + 512]);
            if (tid < 192) {
                __builtin_nontemporal_store(fv, &o4[(size_t)(r    ) * 1280 + 1088 + tid]);
                __builtin_nontemporal_store(fv, &o4[(size_t)(r + 1) * 1280 + 1088 + tid]);
            }
        }
        return;
    }

    // ---------------- GEMM path ----------------
    const int b  = bid >> 3;              // batch
    const int rt = bid & 7;               // row-tile
    const int R0 = rt << 7;               // first of 128 rows
    const int lane = tid & 63;
    const int wid  = tid >> 6;            // 0..7
    const int wr   = wid >> 1;            // 0..3 : rows wr*32
    const int wc   = wid & 1;             // 0..1 : cols wc*128

    const float*    Ab = h2 + ((size_t)b * LOO + R0) * HH;
    const ushort_t* Bb = Bm + (size_t)b * EMAX * HH;

    char* As = smem;                      // [128][80B]
    char* Bs = smem + 10240;              // [256][80B]

    // staging coords: A quad idx (row 0..127, q 0..7), B slot idx (row 0..255, s 0..3)
    const int ar0 = tid >> 3,          aq0 = tid & 7;
    const int ar1 = (tid + 512) >> 3,  aq1 = tid & 7;          // +512 keeps q
    const int br0 = tid >> 2,          bs0 = tid & 3;
    const int br1 = (tid + 512) >> 2,  bs1 = tid & 3;

    f32x4  aR0, aR1;
    bf16x8 bR0, bR1;
    f32x4 acc0[8], acc1[8];
#pragma unroll
    for (int i = 0; i < 8; ++i) {
        acc0[i] = (f32x4){0.f, 0.f, 0.f, 0.f};
        acc1[i] = (f32x4){0.f, 0.f, 0.f, 0.f};
    }

    // prologue loads for k0 = 0
    aR0 = *(const f32x4*)(Ab + (size_t)ar0 * HH + aq0 * 4);
    aR1 = *(const f32x4*)(Ab + (size_t)ar1 * HH + aq1 * 4);
    bR0 = *(const bf16x8*)(Bb + (size_t)br0 * HH + bs0 * 8);
    bR1 = *(const bf16x8*)(Bb + (size_t)br1 * HH + bs1 * 8);

    for (int ks = 0; ks < 24; ++ks) {
        __syncthreads();                  // previous compute done, LDS reusable
        // write staged regs -> LDS (A cvt f32->bf16)
        {
            bf16x4 t0, t1;
            t0[0] = (__bf16)aR0[0]; t0[1] = (__bf16)aR0[1];
            t0[2] = (__bf16)aR0[2]; t0[3] = (__bf16)aR0[3];
            t1[0] = (__bf16)aR1[0]; t1[1] = (__bf16)aR1[1];
            t1[2] = (__bf16)aR1[2]; t1[3] = (__bf16)aR1[3];
            *(bf16x4*)(As + ar0 * 80 + aq0 * 8) = t0;
            *(bf16x4*)(As + ar1 * 80 + aq1 * 8) = t1;
            *(bf16x8*)(Bs + br0 * 80 + bs0 * 16) = bR0;
            *(bf16x8*)(Bs + br1 * 80 + bs1 * 16) = bR1;
        }
        __syncthreads();
        // prefetch next K-step while computing this one
        if (ks < 23) {
            int k0 = (ks + 1) << 5;
            aR0 = *(const f32x4*)(Ab + (size_t)ar0 * HH + k0 + aq0 * 4);
            aR1 = *(const f32x4*)(Ab + (size_t)ar1 * HH + k0 + aq1 * 4);
            bR0 = *(const bf16x8*)(Bb + (size_t)br0 * HH + k0 + bs0 * 8);
            bR1 = *(const bf16x8*)(Bb + (size_t)br1 * HH + k0 + bs1 * 8);
        }
        // fragments + MFMA (K=32 consumed by one mfma per pair)
        {
            const int hb16 = (lane >> 4) << 4;
            bf16x8 af0 = *(const bf16x8*)(As + (wr * 32 +  0 + (lane & 15)) * 80 + hb16);
            bf16x8 af1 = *(const bf16x8*)(As + (wr * 32 + 16 + (lane & 15)) * 80 + hb16);
#pragma unroll
            for (int ni = 0; ni < 8; ++ni) {
                bf16x8 bfv = *(const bf16x8*)(Bs + (wc * 128 + ni * 16 + (lane & 15)) * 80 + hb16);
                acc0[ni] = __builtin_amdgcn_mfma_f32_16x16x32_bf16(af0, bfv, acc0[ni], 0, 0, 0);
                acc1[ni] = __builtin_amdgcn_mfma_f32_16x16x32_bf16(af1, bfv, acc1[ni], 0, 0, 0);
            }
        }
    }

    // epilogue: C/D layout col=lane&15, row=(lane>>4)*4+reg (m89-verified)
    const int em = emitted[b];
    float* outb = out + ((size_t)b * LOO + R0) * OUTW + VV;
    const int rb = wr * 32 + ((lane >> 4) << 2);
#pragma unroll
    for (int ni = 0; ni < 8; ++ni) {
        int l = wc * 128 + ni * 16 + (lane & 15);
        float badd = (l < em) ? 0.0f : -100.0f;
#pragma unroll
        for (int rr = 0; rr < 4; ++rr) {
            outb[(size_t)(rb + rr) * OUTW + l]      = acc0[ni][rr] + badd;
            outb[(size_t)(rb + 16 + rr) * OUTW + l] = acc1[ni][rr] + badd;
        }
    }
}

extern "C" void kernel_launch(void* const* d_in, const int* in_sizes, int n_in,
                              void* d_out, int out_size, void* d_ws, size_t ws_size,
                              hipStream_t stream) {
    const float* h1   = (const float*)d_in[0];   // [8,1024,768]
    const float* h2   = (const float*)d_in[1];   // [8,1024,768]
    const float* lm   = (const float*)d_in[2];   // [8,1024,4096]
    const int*   tags = (const int*)d_in[3];     // [8,1024]
    float* out = (float*)d_out;                  // [8,1024,5120]

    // workspace: attn bf16 [8][256][768] + emitted[8]
    char* ws = (char*)d_ws;
    ushort_t* attn    = (ushort_t*)ws;                 // 3,145,728 B
    int*      emitted = (int*)(ws + 3145728);          // 32 B

    attn_stream_kernel<<<dim3(16, 3, 8), 256, 0, stream>>>(h1, tags, attn, emitted);
    mega2_kernel<<<NGEMM + 1024, 512, 0, stream>>>(h2, attn, emitted, lm, out);
}